// Round 17
// baseline (443.574 us; speedup 1.0000x reference)
//
#include <hip/hip_runtime.h>
#include <cstdint>

typedef short short8 __attribute__((ext_vector_type(8)));
typedef float floatx4 __attribute__((ext_vector_type(4)));
typedef unsigned char uchar;

constexpr int NU = 200000;   // N_USER
constexpr int NI = 100000;   // N_ITEM
constexpr int NEDGE = 1000000;
constexpr int HD = 128;
constexpr int HH = HD * HD;
constexpr int BUK = 1024;    // nodes per bucket
constexpr int EPB = 4096;    // edges per partition block
constexpr int EPT = 16;      // edges per thread (256 thr)
constexpr int MAXBUK = 256;  // >= ceil(NU/BUK)=196
constexpr int NBLK = (NEDGE + EPB - 1) / EPB;   // 245
constexpr int NB_I = (NI + BUK - 1) / BUK;      // 98
constexpr int NB_U = (NU + BUK - 1) / BUK;      // 196
constexpr int LROW = 136;    // LDS row stride in shorts (128 + 8 pad)

// ---- bf16 bit helpers ----
__device__ __forceinline__ float bits2f(short s) {
    return __uint_as_float(((unsigned int)(unsigned short)s) << 16);
}
__device__ __forceinline__ short f2bits(float f) {
    unsigned int u = __float_as_uint(f);
    unsigned int lsb = (u >> 16) & 1u;
    u += 0x7fffu + lsb;   // round-to-nearest-even
    return (short)(u >> 16);
}

// ================= CSR build v3: contention-free count/scan/place =================
__global__ __launch_bounds__(256) void k_cnt3(const int* __restrict__ dst0,
                                              const int* __restrict__ dst1,
                                              const int* __restrict__ dst2,
                                              int* __restrict__ cnts) {
    __shared__ int cnt[MAXBUK];
    const int g = blockIdx.x / NBLK;
    const int blk = blockIdx.x % NBLK;
    const int* dst = (g == 0) ? dst0 : (g == 1) ? dst1 : dst2;
    int t = threadIdx.x;
    for (int b = t; b < MAXBUK; b += 256) cnt[b] = 0;
    __syncthreads();
    const int e0 = blk * EPB + t * EPT;
#pragma unroll
    for (int i = 0; i < EPT; ++i) {
        int e = e0 + i;
        if (e < NEDGE) atomicAdd(&cnt[dst[e] >> 10], 1);
    }
    __syncthreads();
    for (int b = t; b < MAXBUK; b += 256)
        cnts[(size_t)(g * NBLK + blk) * MAXBUK + b] = cnt[b];
}

__global__ __launch_bounds__(256) void k_bases3(const int* __restrict__ cnts,
                                                int* __restrict__ base,
                                                int* __restrict__ bbase,
                                                int* __restrict__ off0,
                                                int* __restrict__ off1,
                                                int* __restrict__ off2) {
    __shared__ int s[256];
    const int g = blockIdx.x;
    const int t = threadIdx.x;
    int tot = 0;
    for (int blk = 0; blk < NBLK; ++blk)
        tot += cnts[(size_t)(g * NBLK + blk) * MAXBUK + t];
    s[t] = tot;
    __syncthreads();
    for (int d = 1; d < 256; d <<= 1) {
        int u = (t >= d) ? s[t - d] : 0;
        __syncthreads();
        s[t] += u;
        __syncthreads();
    }
    int bb = s[t] - tot;
    bbase[g * 257 + t] = bb;
    if (t == 255) bbase[g * 257 + 256] = bb + tot;
    int run = bb;
    for (int blk = 0; blk < NBLK; ++blk) {
        size_t idx = (size_t)(g * NBLK + blk) * MAXBUK + t;
        base[idx] = run;
        run += cnts[idx];
    }
    if (t == 0) {
        if (g == 0) off0[NI] = NEDGE;
        else if (g == 1) off1[NU] = NEDGE;
        else off2[NU] = NEDGE;
    }
}

__global__ __launch_bounds__(256) void k_part3(const int* __restrict__ src0,
                                               const int* __restrict__ dst0,
                                               const int* __restrict__ src1,
                                               const int* __restrict__ dst1,
                                               const int* __restrict__ src2,
                                               const int* __restrict__ dst2,
                                               const int* __restrict__ base,
                                               int* __restrict__ pairs) {
    __shared__ int cnt[MAXBUK];
    __shared__ int bas[MAXBUK];
    const int g = blockIdx.x / NBLK;
    const int blk = blockIdx.x % NBLK;
    const int* src = (g == 0) ? src0 : (g == 1) ? src1 : src2;
    const int* dst = (g == 0) ? dst0 : (g == 1) ? dst1 : dst2;
    int* pg = pairs + (size_t)g * NEDGE;
    int t = threadIdx.x;
    for (int b = t; b < MAXBUK; b += 256) cnt[b] = 0;
    __syncthreads();
    const int e0 = blk * EPB + t * EPT;
    int sv[EPT], dv[EPT], rk[EPT];
#pragma unroll
    for (int i = 0; i < EPT; ++i) {
        int e = e0 + i;
        bool ok = e < NEDGE;
        dv[i] = ok ? dst[e] : 0;
        sv[i] = ok ? src[e] : 0;
    }
#pragma unroll
    for (int i = 0; i < EPT; ++i)
        rk[i] = (e0 + i < NEDGE) ? atomicAdd(&cnt[dv[i] >> 10], 1) : 0;
    __syncthreads();
    for (int b = t; b < MAXBUK; b += 256)
        bas[b] = base[(size_t)(g * NBLK + blk) * MAXBUK + b];
    __syncthreads();
#pragma unroll
    for (int i = 0; i < EPT; ++i) {
        if (e0 + i < NEDGE)
            pg[bas[dv[i] >> 10] + rk[i]] = sv[i] | ((dv[i] & 1023) << 18);
    }
}

__global__ __launch_bounds__(256) void k_place3(const int* __restrict__ pairs,
                                                const int* __restrict__ bbase,
                                                int* __restrict__ off0, int* __restrict__ esrc0,
                                                int* __restrict__ off1, int* __restrict__ esrc1,
                                                int* __restrict__ off2, int* __restrict__ esrc2) {
    __shared__ int cnt[BUK];
    __shared__ int ts[256];
    int bi = blockIdx.x;
    int g, bloc, N;
    int* off;
    int* esrc;
    if (bi < NB_I) { g = 0; bloc = bi; N = NI; off = off0; esrc = esrc0; }
    else if (bi < NB_I + NB_U) { g = 1; bloc = bi - NB_I; N = NU; off = off1; esrc = esrc1; }
    else { g = 2; bloc = bi - NB_I - NB_U; N = NU; off = off2; esrc = esrc2; }
    const int* pg = pairs + (size_t)g * NEDGE;
    const int b0 = bbase[g * 257 + bloc];
    const int b1 = bbase[g * 257 + bloc + 1];
    const int t = threadIdx.x;
    for (int i = t; i < BUK; i += 256) cnt[i] = 0;
    __syncthreads();
    for (int j = b0 + t; j < b1; j += 256) atomicAdd(&cnt[pg[j] >> 18], 1);
    __syncthreads();
    const int idx = t * 4;
    int c0 = cnt[idx], c1 = cnt[idx + 1], c2 = cnt[idx + 2], c3 = cnt[idx + 3];
    int ssum = c0 + c1 + c2 + c3;
    ts[t] = ssum;
    __syncthreads();
    for (int d = 1; d < 256; d <<= 1) {
        int u = (t >= d) ? ts[t - d] : 0;
        __syncthreads();
        ts[t] += u;
        __syncthreads();
    }
    int o = b0 + ts[t] - ssum;
    const int n0 = bloc * BUK;
    int cc[4] = {c0, c1, c2, c3};
#pragma unroll
    for (int i = 0; i < 4; ++i) {
        int n = n0 + idx + i;
        if (n < N) off[n] = o;
        cnt[idx + i] = o;
        o += cc[i];
    }
    __syncthreads();
    for (int j = b0 + t; j < b1; j += 256) {
        int p = pg[j];
        int pos = atomicAdd(&cnt[p >> 18], 1);
        esrc[pos] = p & 0x3FFFF;
    }
}

// ================= weight prep (separate proven kernels) =================
__global__ void k_pack(short* __restrict__ dst, const float* __restrict__ A,
                       const float* __restrict__ B, const float* __restrict__ B2,
                       int KA, int KBr, int NCOL) {
    int l = threadIdx.x;
    int kbt = (KA + KBr) >> 5;
    int nt = blockIdx.x / kbt;
    int kb = blockIdx.x % kbt;
    int col = nt * 16 + (l & 15);
    int k0 = kb * 32 + (l >> 4) * 8;
    short8 o;
#pragma unroll
    for (int j = 0; j < 8; ++j) {
        int k = k0 + j;
        float f;
        if (k < KA) {
            f = A[(size_t)k * NCOL + col];
        } else {
            int k2 = k - KA;
            f = B[(size_t)k2 * NCOL + col];
            if (B2) f += B2[(size_t)k2 * NCOL + col];
        }
        o[j] = f2bits(f);
    }
    *(short8*)(dst + ((size_t)blockIdx.x * 64 + l) * 8) = o;
}

__global__ void k_pack3(short* __restrict__ dst, const float* __restrict__ A,
                        const float* __restrict__ B, const float* __restrict__ C1,
                        const float* __restrict__ C2) {
    int l = threadIdx.x;
    constexpr int kbt = 12;
    int nt = blockIdx.x / kbt;
    int kb = blockIdx.x % kbt;
    int col = nt * 16 + (l & 15);
    int k0 = kb * 32 + (l >> 4) * 8;
    short8 o;
#pragma unroll
    for (int j = 0; j < 8; ++j) {
        int k = k0 + j;
        float f;
        if (k < 128) f = A[(size_t)k * 128 + col];
        else if (k < 256) f = B[(size_t)(k - 128) * 128 + col];
        else f = C1[(size_t)(k - 256) * 128 + col] + C2[(size_t)(k - 256) * 128 + col];
        o[j] = f2bits(f);
    }
    *(short8*)(dst + ((size_t)blockIdx.x * 64 + l) * 8) = o;
}

__global__ void k_foldW(float* __restrict__ dst, const float* __restrict__ Wa,
                        const float* __restrict__ Wb, const float* __restrict__ Wo,
                        int colOff, int NC) {
    int k = blockIdx.x;
    int c = threadIdx.x;
    float a = 0.f;
    for (int t = 0; t < 128; ++t) {
        float w = Wa[(size_t)k * 128 + t];
        if (Wb) w += Wb[(size_t)k * 128 + t];
        a += w * Wo[t * 16 + c];
    }
    dst[(size_t)k * NC + colOff + c] = a;
}

__global__ void k_bfold(float* __restrict__ dst, const float* __restrict__ bl1,
                        const float* __restrict__ bl2, const float* __restrict__ Wo,
                        const float* __restrict__ bo) {
    int c = threadIdx.x;
    float a = 0.f;
    for (int t = 0; t < 128; ++t) a += (bl1[t] + bl2[t]) * Wo[t * 16 + c];
    dst[c] = a + bo[c];
}

__global__ void k_addbias(float* __restrict__ dst, const float* __restrict__ a,
                          const float* __restrict__ b) {
    int i = threadIdx.x;
    dst[i] = a[i] + b[i];
}

// ---- u8 gather-mean, 16-lanes-per-node: lane owns 8 contiguous cols (uint2) ----
__device__ __forceinline__ void gmean8(const uchar* __restrict__ X8,
                                       const float* __restrict__ scale,
                                       const int* __restrict__ off,
                                       const int* __restrict__ esrc,
                                       int node, int ch, float m[8]) {
#pragma unroll
    for (int i = 0; i < 8; ++i) m[i] = 0.f;
    float S = 0.f;
    const int s = off[node], e = off[node + 1];
    int j = s;
    for (; j + 4 <= e; j += 4) {
        const int i0 = esrc[j], i1 = esrc[j + 1], i2 = esrc[j + 2], i3 = esrc[j + 3];
        const float s0 = scale[i0], s1 = scale[i1], s2 = scale[i2], s3 = scale[i3];
        uint2 v0 = *(const uint2*)(X8 + (size_t)i0 * HD + ch * 8);
        uint2 v1 = *(const uint2*)(X8 + (size_t)i1 * HD + ch * 8);
        uint2 v2 = *(const uint2*)(X8 + (size_t)i2 * HD + ch * 8);
        uint2 v3 = *(const uint2*)(X8 + (size_t)i3 * HD + ch * 8);
        S += (s0 + s1) + (s2 + s3);
#pragma unroll
        for (int i = 0; i < 4; ++i) {
            m[i]     += s0 * (float)((v0.x >> (8 * i)) & 0xffu)
                      + s1 * (float)((v1.x >> (8 * i)) & 0xffu)
                      + s2 * (float)((v2.x >> (8 * i)) & 0xffu)
                      + s3 * (float)((v3.x >> (8 * i)) & 0xffu);
            m[4 + i] += s0 * (float)((v0.y >> (8 * i)) & 0xffu)
                      + s1 * (float)((v1.y >> (8 * i)) & 0xffu)
                      + s2 * (float)((v2.y >> (8 * i)) & 0xffu)
                      + s3 * (float)((v3.y >> (8 * i)) & 0xffu);
        }
    }
    for (; j < e; ++j) {
        const int i0 = esrc[j];
        const float s0 = scale[i0];
        uint2 v = *(const uint2*)(X8 + (size_t)i0 * HD + ch * 8);
        S += s0;
#pragma unroll
        for (int i = 0; i < 4; ++i) {
            m[i]     = fmaf(s0, (float)((v.x >> (8 * i)) & 0xffu), m[i]);
            m[4 + i] = fmaf(s0, (float)((v.y >> (8 * i)) & 0xffu), m[4 + i]);
        }
    }
    const int d = e - s;
    const float inv = 1.f / (float)(d > 0 ? d : 1);
    const float corr = 128.f * S;
#pragma unroll
    for (int i = 0; i < 8; ++i) m[i] = (m[i] - corr) * inv;
}

// ---- u8 self-term A-frag: 8 cols at k = kb*32 + g*8 of row ar, dequantized ----
__device__ __forceinline__ short8 self_u8(const uchar* __restrict__ X8, float sA,
                                          int ar, int g, int kb) {
    uint2 v = *(const uint2*)(X8 + (size_t)ar * HD + kb * 32 + g * 8);
    const float c = 128.f * sA;
    short8 f;
#pragma unroll
    for (int i = 0; i < 4; ++i) {
        f[i]     = f2bits(sA * (float)((v.x >> (8 * i)) & 0xffu) - c);
        f[4 + i] = f2bits(sA * (float)((v.y >> (8 * i)) & 0xffu) - c);
    }
    return f;
}

// ================= merged SAGE layer-0 + folded layer-1 projection =================
// block = 16 nodes. Phase 1: each wave gathers 4 nodes (16 lanes/node) -> LDS
// tiles. Phase 2: waves split the layer-0 MFMA nt-tiles (self term from u8).
// Phase 3: bias+leaky -> tileO. Phase 4: fold-MFMA -> Y.
__global__ __launch_bounds__(256) void k_sage_all(
        const uchar* __restrict__ hu8, const float* __restrict__ scU,
        const uchar* __restrict__ hi8, const float* __restrict__ scI,
        const int* __restrict__ off_rates, const int* __restrict__ esrc_rates,
        const int* __restrict__ off_rated, const int* __restrict__ esrc_rated,
        const int* __restrict__ off_fol, const int* __restrict__ esrc_fol,
        const short* __restrict__ WpI, const float* __restrict__ biasI,
        const short* __restrict__ pYI,
        const short* __restrict__ WpU, const float* __restrict__ biasU,
        const short* __restrict__ pYU,
        short* __restrict__ YI, short* __restrict__ YZ, int gU) {
    __shared__ short tileA[16 * LROW];
    __shared__ short tileB[16 * LROW];
    __shared__ short tileO[16 * LROW];
    const int lane = threadIdx.x & 63;
    const int wv = threadIdx.x >> 6;
    const int nl = lane >> 4;        // node-local within wave (0..3)
    const int ch = lane & 15;        // col-chunk (8 cols each)
    const int colL = lane & 15;
    const int g = lane >> 4;

    if ((int)blockIdx.x < gU) {
        // ---------------- user path ----------------
        const int r0 = blockIdx.x * 16;
        const int lnode = wv * 4 + nl;
        int node = r0 + lnode;
        if (node >= NU) node = NU - 1;

        float m[8];
        gmean8(hi8, scI, off_rated, esrc_rated, node, ch, m);
#pragma unroll
        for (int i = 0; i < 8; ++i) tileA[lnode * LROW + ch * 8 + i] = f2bits(m[i]);
        gmean8(hu8, scU, off_fol, esrc_fol, node, ch, m);
#pragma unroll
        for (int i = 0; i < 8; ++i) tileB[lnode * LROW + ch * 8 + i] = f2bits(m[i]);
        __syncthreads();

        short8 afrag[12];
        {
            const short* ra = tileA + colL * LROW + g * 8;
            const short* rb = tileB + colL * LROW + g * 8;
#pragma unroll
            for (int kb = 0; kb < 4; ++kb) {
                afrag[kb] = *(const short8*)(ra + kb * 32);
                afrag[4 + kb] = *(const short8*)(rb + kb * 32);
            }
            int ar = r0 + colL;
            if (ar >= NU) ar = NU - 1;
            const float sA = scU[ar];
#pragma unroll
            for (int kb = 0; kb < 4; ++kb) afrag[8 + kb] = self_u8(hu8, sA, ar, g, kb);
        }

        floatx4 acc[2];
#pragma unroll
        for (int t2 = 0; t2 < 2; ++t2) acc[t2] = (floatx4){0.f, 0.f, 0.f, 0.f};
        const short8* wp = (const short8*)WpU + lane;
#pragma unroll
        for (int t2 = 0; t2 < 2; ++t2) {
            const int nt = wv * 2 + t2;
#pragma unroll
            for (int kb = 0; kb < 12; ++kb) {
                short8 b = wp[(nt * 12 + kb) * 64];
                acc[t2] = __builtin_amdgcn_mfma_f32_16x16x32_bf16(afrag[kb], b, acc[t2], 0, 0, 0);
            }
        }
#pragma unroll
        for (int t2 = 0; t2 < 2; ++t2) {
            const int nt = wv * 2 + t2;
            float bv = biasU[nt * 16 + colL];
#pragma unroll
            for (int r = 0; r < 4; ++r) {
                float x = acc[t2][r] + bv;
                x = (x >= 0.f) ? x : 0.01f * x;
                tileO[(g * 4 + r) * LROW + nt * 16 + colL] = f2bits(x);
            }
        }
        __syncthreads();

        if (wv < 2) {
            short8 af[4];
            const short* rp = tileO + colL * LROW + g * 8;
#pragma unroll
            for (int kb = 0; kb < 4; ++kb) af[kb] = *(const short8*)(rp + kb * 32);
            floatx4 a2 = (floatx4){0.f, 0.f, 0.f, 0.f};
            const short8* fp = (const short8*)pYU + lane;
#pragma unroll
            for (int kb = 0; kb < 4; ++kb) {
                short8 b = fp[(wv * 4 + kb) * 64];
                a2 = __builtin_amdgcn_mfma_f32_16x16x32_bf16(af[kb], b, a2, 0, 0, 0);
            }
            const int rbase = r0 + g * 4;
#pragma unroll
            for (int r = 0; r < 4; ++r) {
                int row = rbase + r;
                if (row < NU) YZ[(size_t)row * 32 + wv * 16 + colL] = f2bits(a2[r]);
            }
        }
    } else {
        // ---------------- item path ----------------
        const int b = blockIdx.x - gU;
        const int r0 = b * 16;
        const int lnode = wv * 4 + nl;
        int node = r0 + lnode;
        if (node >= NI) node = NI - 1;

        float m[8];
        gmean8(hu8, scU, off_rates, esrc_rates, node, ch, m);
#pragma unroll
        for (int i = 0; i < 8; ++i) tileA[lnode * LROW + ch * 8 + i] = f2bits(m[i]);
        __syncthreads();

        short8 afrag[8];
        {
            const short* ra = tileA + colL * LROW + g * 8;
#pragma unroll
            for (int kb = 0; kb < 4; ++kb) afrag[kb] = *(const short8*)(ra + kb * 32);
            int ar = r0 + colL;
            if (ar >= NI) ar = NI - 1;
            const float sA = scI[ar];
#pragma unroll
            for (int kb = 0; kb < 4; ++kb) afrag[4 + kb] = self_u8(hi8, sA, ar, g, kb);
        }

        floatx4 acc[2];
#pragma unroll
        for (int t2 = 0; t2 < 2; ++t2) acc[t2] = (floatx4){0.f, 0.f, 0.f, 0.f};
        const short8* wp = (const short8*)WpI + lane;
#pragma unroll
        for (int t2 = 0; t2 < 2; ++t2) {
            const int nt = wv * 2 + t2;
#pragma unroll
            for (int kb = 0; kb < 8; ++kb) {
                short8 b = wp[(nt * 8 + kb) * 64];
                acc[t2] = __builtin_amdgcn_mfma_f32_16x16x32_bf16(afrag[kb], b, acc[t2], 0, 0, 0);
            }
        }
#pragma unroll
        for (int t2 = 0; t2 < 2; ++t2) {
            const int nt = wv * 2 + t2;
            float bv = biasI[nt * 16 + colL];
#pragma unroll
            for (int r = 0; r < 4; ++r) {
                float x = acc[t2][r] + bv;
                x = (x >= 0.f) ? x : 0.01f * x;
                tileO[(g * 4 + r) * LROW + nt * 16 + colL] = f2bits(x);
            }
        }
        __syncthreads();

        if (wv == 0) {
            short8 af[4];
            const short* rp = tileO + colL * LROW + g * 8;
#pragma unroll
            for (int kb = 0; kb < 4; ++kb) af[kb] = *(const short8*)(rp + kb * 32);
            floatx4 a2 = (floatx4){0.f, 0.f, 0.f, 0.f};
            const short8* fp = (const short8*)pYI + lane;
#pragma unroll
            for (int kb = 0; kb < 4; ++kb) {
                short8 b = fp[kb * 64];
                a2 = __builtin_amdgcn_mfma_f32_16x16x32_bf16(af[kb], b, a2, 0, 0, 0);
            }
            const int rbase = r0 + g * 4;
#pragma unroll
            for (int r = 0; r < 4; ++r) {
                int row = rbase + r;
                if (row < NI) YI[(size_t)row * 16 + colL] = f2bits(a2[r]);
            }
        }
    }
}

// ================= input projections (merged): u8 + scale ONLY (no bf16 copy) =================
template <int KB1>
__device__ __forceinline__ void mm_body(int bid, const float* __restrict__ A1,
                                        const short* __restrict__ Wp,
                                        const float* __restrict__ bias,
                                        uchar* __restrict__ U8,
                                        float* __restrict__ scale, int M,
                                        int lane, int wv) {
    const int r0 = bid * 128 + wv * 32;
    const int g = lane >> 4;
    const int ksub = g * 8;
    const int colL = lane & 15;
    short8 afrag[2][KB1];
#pragma unroll
    for (int h = 0; h < 2; ++h) {
        int ar = r0 + h * 16 + colL;
        if (ar >= M) ar = M - 1;
        const float* p = A1 + (size_t)ar * (KB1 * 32) + ksub;
#pragma unroll
        for (int kb = 0; kb < KB1; ++kb) {
            short8 f;
#pragma unroll
            for (int j = 0; j < 8; ++j) f[j] = f2bits(p[kb * 32 + j]);
            afrag[h][kb] = f;
        }
    }
    floatx4 acc[2][8];
#pragma unroll
    for (int h = 0; h < 2; ++h)
#pragma unroll
        for (int nt = 0; nt < 8; ++nt) acc[h][nt] = (floatx4){0.f, 0.f, 0.f, 0.f};
    const short8* wp = (const short8*)Wp + lane;
#pragma unroll
    for (int nt = 0; nt < 8; ++nt)
#pragma unroll
        for (int kb = 0; kb < KB1; ++kb) {
            short8 b = wp[(nt * KB1 + kb) * 64];
            acc[0][nt] = __builtin_amdgcn_mfma_f32_16x16x32_bf16(afrag[0][kb], b, acc[0][nt], 0, 0, 0);
            acc[1][nt] = __builtin_amdgcn_mfma_f32_16x16x32_bf16(afrag[1][kb], b, acc[1][nt], 0, 0, 0);
        }
#pragma unroll
    for (int h = 0; h < 2; ++h) {
#pragma unroll
        for (int r = 0; r < 4; ++r) {
            const int row = r0 + h * 16 + g * 4 + r;
            float v[8];
            float m = 0.f;
#pragma unroll
            for (int nt = 0; nt < 8; ++nt) {
                v[nt] = acc[h][nt][r] + bias[nt * 16 + colL];
                m = fmaxf(m, fabsf(v[nt]));
            }
#pragma unroll
            for (int x = 1; x < 16; x <<= 1) m = fmaxf(m, __shfl_xor(m, x, 16));
            const float invq = (m > 0.f) ? 127.f / m : 0.f;
            if (row < M) {
#pragma unroll
                for (int nt = 0; nt < 8; ++nt) {
                    U8[(size_t)row * HD + nt * 16 + colL] =
                        (uchar)((int)rintf(v[nt] * invq) + 128);
                }
                if (colL == 0) scale[row] = m * (1.f / 127.f);
            }
        }
    }
}

__global__ __launch_bounds__(256) void k_mm2(const float* __restrict__ xu,
                                             const short* __restrict__ pWu,
                                             const float* __restrict__ bu,
                                             uchar* __restrict__ hu8,
                                             float* __restrict__ scU,
                                             const float* __restrict__ xi,
                                             const short* __restrict__ pWi,
                                             const float* __restrict__ bi,
                                             uchar* __restrict__ hi8,
                                             float* __restrict__ scI, int gU2) {
    const int lane = threadIdx.x & 63;
    const int wv = threadIdx.x >> 6;
    if ((int)blockIdx.x < gU2)
        mm_body<2>(blockIdx.x, xu, pWu, bu, hu8, scU, NU, lane, wv);
    else
        mm_body<4>(blockIdx.x - gU2, xi, pWi, bi, hi8, scI, NI, lane, wv);
}

// ================= final output =================
__global__ __launch_bounds__(256) void k_out(const short* __restrict__ YZ,
                                             const short* __restrict__ YI,
                                             const int* __restrict__ off_f,
                                             const int* __restrict__ esrc_f,
                                             const int* __restrict__ off_r,
                                             const int* __restrict__ esrc_r,
                                             const float* __restrict__ bias16,
                                             float* __restrict__ out, int N) {
    int t = threadIdx.x;
    int node = blockIdx.x * 128 + (t >> 1);
    int half = t & 1;
    if (node >= N) return;
    const int c0 = half * 8;

    float a[8] = {0.f, 0.f, 0.f, 0.f, 0.f, 0.f, 0.f, 0.f};
    {
        const int s = off_f[node], e = off_f[node + 1];
        int j = s;
        for (; j + 4 <= e; j += 4) {
            short8 v0 = *(const short8*)(YZ + (size_t)esrc_f[j] * 32 + c0);
            short8 v1 = *(const short8*)(YZ + (size_t)esrc_f[j + 1] * 32 + c0);
            short8 v2 = *(const short8*)(YZ + (size_t)esrc_f[j + 2] * 32 + c0);
            short8 v3 = *(const short8*)(YZ + (size_t)esrc_f[j + 3] * 32 + c0);
#pragma unroll
            for (int i = 0; i < 8; ++i)
                a[i] += (bits2f(v0[i]) + bits2f(v1[i])) + (bits2f(v2[i]) + bits2f(v3[i]));
        }
        for (; j < e; ++j) {
            short8 v = *(const short8*)(YZ + (size_t)esrc_f[j] * 32 + c0);
#pragma unroll
            for (int i = 0; i < 8; ++i) a[i] += bits2f(v[i]);
        }
        int d = e - s;
        float inv = 1.f / (float)(d > 0 ? d : 1);
#pragma unroll
        for (int i = 0; i < 8; ++i) a[i] *= inv;
    }
    {
        float b[8] = {0.f, 0.f, 0.f, 0.f, 0.f, 0.f, 0.f, 0.f};
        const int s = off_r[node], e = off_r[node + 1];
        int j = s;
        for (; j + 4 <= e; j += 4) {
            short8 v0 = *(const short8*)(YI + (size_t)esrc_r[j] * 16 + c0);
            short8 v1 = *(const short8*)(YI + (size_t)esrc_r[j + 1] * 16 + c0);
            short8 v2 = *(const short8*)(YI + (size_t)esrc_r[j + 2] * 16 + c0);
            short8 v3 = *(const short8*)(YI + (size_t)esrc_r[j + 3] * 16 + c0);
#pragma unroll
            for (int i = 0; i < 8; ++i)
                b[i] += (bits2f(v0[i]) + bits2f(v1[i])) + (bits2f(v2[i]) + bits2f(v3[i]));
        }
        for (; j < e; ++j) {
            short8 v = *(const short8*)(YI + (size_t)esrc_r[j] * 16 + c0);
#pragma unroll
            for (int i = 0; i < 8; ++i) b[i] += bits2f(v[i]);
        }
        int d = e - s;
        float inv = 1.f / (float)(d > 0 ? d : 1);
#pragma unroll
        for (int i = 0; i < 8; ++i) a[i] += b[i] * inv;
    }
    short8 z = *(const short8*)(YZ + (size_t)node * 32 + 16 + c0);
#pragma unroll
    for (int i = 0; i < 8; ++i)
        out[(size_t)node * 16 + c0 + i] = a[i] + bits2f(z[i]) + bias16[c0 + i];
}

// ================= launch =================
extern "C" void kernel_launch(void* const* d_in, const int* in_sizes, int n_in,
                              void* d_out, int out_size, void* d_ws, size_t ws_size,
                              hipStream_t stream) {
    const float* x_user    = (const float*)d_in[0];
    const float* x_item    = (const float*)d_in[1];
    const int* src_rates   = (const int*)d_in[2];
    const int* dst_rates   = (const int*)d_in[3];
    const int* src_rated   = (const int*)d_in[4];
    const int* dst_rated   = (const int*)d_in[5];
    const int* src_fol     = (const int*)d_in[6];
    const int* dst_fol     = (const int*)d_in[7];
    const float* W_in_user = (const float*)d_in[8];
    const float* b_in_user = (const float*)d_in[9];
    const float* W_in_item = (const float*)d_in[10];
    const float* b_in_item = (const float*)d_in[11];
    const float* Wl_rates  = (const float*)d_in[12];
    const float* bl_rates  = (const float*)d_in[13];
    const float* Wr_rates  = (const float*)d_in[14];
    const float* Wl_rated  = (const float*)d_in[15];
    const float* bl_rated  = (const float*)d_in[16];
    const float* Wr_rated  = (const float*)d_in[17];
    const float* Wl_fol    = (const float*)d_in[18];
    const float* bl_fol    = (const float*)d_in[19];
    const float* Wr_fol    = (const float*)d_in[20];
    const float* W_out     = (const float*)d_in[21];
    const float* b_out     = (const float*)d_in[22];
    float* out = (float*)d_out;

    char* w = (char*)d_ws;
    size_t used = 0;
    auto alloc = [&](size_t bytes) -> void* {
        void* p = w + used;
        used += (bytes + 255) & ~(size_t)255;
        return p;
    };
    uchar* hu8  = (uchar*)alloc((size_t)NU * HD);
    uchar* hi8  = (uchar*)alloc((size_t)NI * HD);
    float* scU  = (float*)alloc((size_t)NU * 4);
    float* scI  = (float*)alloc((size_t)NI * 4);
    short* YZ   = (short*)alloc((size_t)NU * 32 * 2);
    short* YI   = (short*)alloc((size_t)NI * 16 * 2);

    int* off_rates  = (int*)alloc((size_t)(NI + 1) * 4);
    int* esrc_rates = (int*)alloc((size_t)NEDGE * 4);
    int* off_rated  = (int*)alloc((size_t)(NU + 1) * 4);
    int* esrc_rated = (int*)alloc((size_t)NEDGE * 4);
    int* off_fol    = (int*)alloc((size_t)(NU + 1) * 4);
    int* esrc_fol   = (int*)alloc((size_t)NEDGE * 4);
    int* pairs      = (int*)alloc((size_t)3 * NEDGE * 4);
    int* cnts       = (int*)alloc((size_t)3 * NBLK * MAXBUK * 4);
    int* base       = (int*)alloc((size_t)3 * NBLK * MAXBUK * 4);
    int* bbase      = (int*)alloc((size_t)3 * 257 * 4);

    short* pWu     = (short*)alloc(8 * 2 * 64 * 8 * 2);
    short* pWi     = (short*)alloc(8 * 4 * 64 * 8 * 2);
    short* pRates0 = (short*)alloc(8 * 8 * 64 * 8 * 2);
    short* pUser0  = (short*)alloc(8 * 12 * 64 * 8 * 2);
    float* WfU     = (float*)alloc(128 * 32 * 4);
    float* WfI     = (float*)alloc(128 * 16 * 4);
    short* pYU     = (short*)alloc(2 * 4 * 64 * 8 * 2);
    short* pYI     = (short*)alloc(1 * 4 * 64 * 8 * 2);
    float* bSum0   = (float*)alloc(128 * 4);
    float* bias16  = (float*)alloc(16 * 4);
    if (used > ws_size) return;   // diagnostic signature: output stays zero

    // ---- CSR build v3 (contention-free, all 3 graphs merged) ----
    k_cnt3<<<3 * NBLK, 256, 0, stream>>>(dst_rates, dst_rated, dst_fol, cnts);
    k_bases3<<<3, 256, 0, stream>>>(cnts, base, bbase, off_rates, off_rated, off_fol);
    k_part3<<<3 * NBLK, 256, 0, stream>>>(src_rates, dst_rates, src_rated, dst_rated,
                                          src_fol, dst_fol, base, pairs);
    k_place3<<<NB_I + 2 * NB_U, 256, 0, stream>>>(pairs, bbase,
                                                  off_rates, esrc_rates,
                                                  off_rated, esrc_rated,
                                                  off_fol, esrc_fol);

    // ---- weight prep (separate proven kernels) ----
    k_pack<<<16, 64, 0, stream>>>(pWu, W_in_user, nullptr, nullptr, 64, 0, 128);
    k_pack<<<32, 64, 0, stream>>>(pWi, W_in_item, nullptr, nullptr, 128, 0, 128);
    k_pack<<<64, 64, 0, stream>>>(pRates0, Wl_rates, Wr_rates, nullptr, 128, 128, 128);
    k_pack3<<<96, 64, 0, stream>>>(pUser0, Wl_rated, Wl_fol, Wr_rated, Wr_fol);
    k_addbias<<<1, 128, 0, stream>>>(bSum0, bl_rated, bl_fol);
    k_foldW<<<128, 16, 0, stream>>>(WfU, Wl_fol + HH,   nullptr,     W_out, 0, 32);
    k_foldW<<<128, 16, 0, stream>>>(WfU, Wr_rated + HH, Wr_fol + HH, W_out, 16, 32);
    k_foldW<<<128, 16, 0, stream>>>(WfI, Wl_rated + HH, nullptr,     W_out, 0, 16);
    k_pack<<<8, 64, 0, stream>>>(pYU, WfU, nullptr, nullptr, 128, 0, 32);
    k_pack<<<4, 64, 0, stream>>>(pYI, WfI, nullptr, nullptr, 128, 0, 16);
    k_bfold<<<1, 16, 0, stream>>>(bias16, bl_rated + 128, bl_fol + 128, W_out, b_out);

    const int gU2 = (NU + 127) / 128;  // 1563
    const int gI2 = (NI + 127) / 128;  // 782
    const int gU  = (NU + 15) / 16;    // 12500
    const int gI  = (NI + 15) / 16;    // 6250

    // ---- input projections (merged) -> u8 + scale only ----
    k_mm2<<<gU2 + gI2, 256, 0, stream>>>(x_user, pWu, b_in_user, hu8, scU,
                                         x_item, pWi, b_in_item, hi8, scI, gU2);

    // ---- merged layer-0 SAGE (coalesced u8 gathers, u8 self-term) + folded layer-1 ----
    k_sage_all<<<gU + gI, 256, 0, stream>>>(
        hu8, scU, hi8, scI,
        off_rates, esrc_rates, off_rated, esrc_rated, off_fol, esrc_fol,
        pRates0, bl_rates, pYI, pUser0, bSum0, pYU, YI, YZ, gU);

    // ---- final: dual 16-dim gather-mean + residual + bias -> fp32 out ----
    k_out<<<(NU + 127) / 128, 256, 0, stream>>>(
        YZ, YI, off_fol, esrc_fol, off_rated, esrc_rated, bias16, out, NU);
}

// Round 18
// 420.285 us; speedup vs baseline: 1.0554x; 1.0554x over previous
//
#include <hip/hip_runtime.h>
#include <cstdint>

typedef short short8 __attribute__((ext_vector_type(8)));
typedef float floatx4 __attribute__((ext_vector_type(4)));
typedef unsigned char uchar;

constexpr int NU = 200000;   // N_USER
constexpr int NI = 100000;   // N_ITEM
constexpr int NEDGE = 1000000;
constexpr int HD = 128;
constexpr int HH = HD * HD;
constexpr int BUK = 1024;    // nodes per bucket
constexpr int EPB = 4096;    // edges per partition block
constexpr int EPT = 16;      // edges per thread (256 thr)
constexpr int MAXBUK = 256;  // >= ceil(NU/BUK)=196
constexpr int NBLK = (NEDGE + EPB - 1) / EPB;   // 245
constexpr int NB_I = (NI + BUK - 1) / BUK;      // 98
constexpr int NB_U = (NU + BUK - 1) / BUK;      // 196
constexpr int LROW = 136;    // LDS row stride in shorts (128 + 8 pad)

// ---- bf16 bit helpers ----
__device__ __forceinline__ float bits2f(short s) {
    return __uint_as_float(((unsigned int)(unsigned short)s) << 16);
}
__device__ __forceinline__ short f2bits(float f) {
    unsigned int u = __float_as_uint(f);
    unsigned int lsb = (u >> 16) & 1u;
    u += 0x7fffu + lsb;   // round-to-nearest-even
    return (short)(u >> 16);
}

// ================= CSR build v3: contention-free count/scan/place =================
__global__ __launch_bounds__(256) void k_cnt3(const int* __restrict__ dst0,
                                              const int* __restrict__ dst1,
                                              const int* __restrict__ dst2,
                                              int* __restrict__ cnts) {
    __shared__ int cnt[MAXBUK];
    const int g = blockIdx.x / NBLK;
    const int blk = blockIdx.x % NBLK;
    const int* dst = (g == 0) ? dst0 : (g == 1) ? dst1 : dst2;
    int t = threadIdx.x;
    for (int b = t; b < MAXBUK; b += 256) cnt[b] = 0;
    __syncthreads();
    const int e0 = blk * EPB + t * EPT;
#pragma unroll
    for (int i = 0; i < EPT; ++i) {
        int e = e0 + i;
        if (e < NEDGE) atomicAdd(&cnt[dst[e] >> 10], 1);
    }
    __syncthreads();
    for (int b = t; b < MAXBUK; b += 256)
        cnts[(size_t)(g * NBLK + blk) * MAXBUK + b] = cnt[b];
}

__global__ __launch_bounds__(256) void k_bases3(const int* __restrict__ cnts,
                                                int* __restrict__ base,
                                                int* __restrict__ bbase,
                                                int* __restrict__ off0,
                                                int* __restrict__ off1,
                                                int* __restrict__ off2) {
    __shared__ int s[256];
    const int g = blockIdx.x;
    const int t = threadIdx.x;
    int tot = 0;
    for (int blk = 0; blk < NBLK; ++blk)
        tot += cnts[(size_t)(g * NBLK + blk) * MAXBUK + t];
    s[t] = tot;
    __syncthreads();
    for (int d = 1; d < 256; d <<= 1) {
        int u = (t >= d) ? s[t - d] : 0;
        __syncthreads();
        s[t] += u;
        __syncthreads();
    }
    int bb = s[t] - tot;
    bbase[g * 257 + t] = bb;
    if (t == 255) bbase[g * 257 + 256] = bb + tot;
    int run = bb;
    for (int blk = 0; blk < NBLK; ++blk) {
        size_t idx = (size_t)(g * NBLK + blk) * MAXBUK + t;
        base[idx] = run;
        run += cnts[idx];
    }
    if (t == 0) {
        if (g == 0) off0[NI] = NEDGE;
        else if (g == 1) off1[NU] = NEDGE;
        else off2[NU] = NEDGE;
    }
}

__global__ __launch_bounds__(256) void k_part3(const int* __restrict__ src0,
                                               const int* __restrict__ dst0,
                                               const int* __restrict__ src1,
                                               const int* __restrict__ dst1,
                                               const int* __restrict__ src2,
                                               const int* __restrict__ dst2,
                                               const int* __restrict__ base,
                                               int* __restrict__ pairs) {
    __shared__ int cnt[MAXBUK];
    __shared__ int bas[MAXBUK];
    const int g = blockIdx.x / NBLK;
    const int blk = blockIdx.x % NBLK;
    const int* src = (g == 0) ? src0 : (g == 1) ? src1 : src2;
    const int* dst = (g == 0) ? dst0 : (g == 1) ? dst1 : dst2;
    int* pg = pairs + (size_t)g * NEDGE;
    int t = threadIdx.x;
    for (int b = t; b < MAXBUK; b += 256) cnt[b] = 0;
    __syncthreads();
    const int e0 = blk * EPB + t * EPT;
    int sv[EPT], dv[EPT], rk[EPT];
#pragma unroll
    for (int i = 0; i < EPT; ++i) {
        int e = e0 + i;
        bool ok = e < NEDGE;
        dv[i] = ok ? dst[e] : 0;
        sv[i] = ok ? src[e] : 0;
    }
#pragma unroll
    for (int i = 0; i < EPT; ++i)
        rk[i] = (e0 + i < NEDGE) ? atomicAdd(&cnt[dv[i] >> 10], 1) : 0;
    __syncthreads();
    for (int b = t; b < MAXBUK; b += 256)
        bas[b] = base[(size_t)(g * NBLK + blk) * MAXBUK + b];
    __syncthreads();
#pragma unroll
    for (int i = 0; i < EPT; ++i) {
        if (e0 + i < NEDGE)
            pg[bas[dv[i] >> 10] + rk[i]] = sv[i] | ((dv[i] & 1023) << 18);
    }
}

__global__ __launch_bounds__(256) void k_place3(const int* __restrict__ pairs,
                                                const int* __restrict__ bbase,
                                                int* __restrict__ off0, int* __restrict__ esrc0,
                                                int* __restrict__ off1, int* __restrict__ esrc1,
                                                int* __restrict__ off2, int* __restrict__ esrc2) {
    __shared__ int cnt[BUK];
    __shared__ int ts[256];
    int bi = blockIdx.x;
    int g, bloc, N;
    int* off;
    int* esrc;
    if (bi < NB_I) { g = 0; bloc = bi; N = NI; off = off0; esrc = esrc0; }
    else if (bi < NB_I + NB_U) { g = 1; bloc = bi - NB_I; N = NU; off = off1; esrc = esrc1; }
    else { g = 2; bloc = bi - NB_I - NB_U; N = NU; off = off2; esrc = esrc2; }
    const int* pg = pairs + (size_t)g * NEDGE;
    const int b0 = bbase[g * 257 + bloc];
    const int b1 = bbase[g * 257 + bloc + 1];
    const int t = threadIdx.x;
    for (int i = t; i < BUK; i += 256) cnt[i] = 0;
    __syncthreads();
    for (int j = b0 + t; j < b1; j += 256) atomicAdd(&cnt[pg[j] >> 18], 1);
    __syncthreads();
    const int idx = t * 4;
    int c0 = cnt[idx], c1 = cnt[idx + 1], c2 = cnt[idx + 2], c3 = cnt[idx + 3];
    int ssum = c0 + c1 + c2 + c3;
    ts[t] = ssum;
    __syncthreads();
    for (int d = 1; d < 256; d <<= 1) {
        int u = (t >= d) ? ts[t - d] : 0;
        __syncthreads();
        ts[t] += u;
        __syncthreads();
    }
    int o = b0 + ts[t] - ssum;
    const int n0 = bloc * BUK;
    int cc[4] = {c0, c1, c2, c3};
#pragma unroll
    for (int i = 0; i < 4; ++i) {
        int n = n0 + idx + i;
        if (n < N) off[n] = o;
        cnt[idx + i] = o;
        o += cc[i];
    }
    __syncthreads();
    for (int j = b0 + t; j < b1; j += 256) {
        int p = pg[j];
        int pos = atomicAdd(&cnt[p >> 18], 1);
        esrc[pos] = p & 0x3FFFF;
    }
}

// ================= weight prep (separate proven kernels) =================
__global__ void k_pack(short* __restrict__ dst, const float* __restrict__ A,
                       const float* __restrict__ B, const float* __restrict__ B2,
                       int KA, int KBr, int NCOL) {
    int l = threadIdx.x;
    int kbt = (KA + KBr) >> 5;
    int nt = blockIdx.x / kbt;
    int kb = blockIdx.x % kbt;
    int col = nt * 16 + (l & 15);
    int k0 = kb * 32 + (l >> 4) * 8;
    short8 o;
#pragma unroll
    for (int j = 0; j < 8; ++j) {
        int k = k0 + j;
        float f;
        if (k < KA) {
            f = A[(size_t)k * NCOL + col];
        } else {
            int k2 = k - KA;
            f = B[(size_t)k2 * NCOL + col];
            if (B2) f += B2[(size_t)k2 * NCOL + col];
        }
        o[j] = f2bits(f);
    }
    *(short8*)(dst + ((size_t)blockIdx.x * 64 + l) * 8) = o;
}

__global__ void k_pack3(short* __restrict__ dst, const float* __restrict__ A,
                        const float* __restrict__ B, const float* __restrict__ C1,
                        const float* __restrict__ C2) {
    int l = threadIdx.x;
    constexpr int kbt = 12;
    int nt = blockIdx.x / kbt;
    int kb = blockIdx.x % kbt;
    int col = nt * 16 + (l & 15);
    int k0 = kb * 32 + (l >> 4) * 8;
    short8 o;
#pragma unroll
    for (int j = 0; j < 8; ++j) {
        int k = k0 + j;
        float f;
        if (k < 128) f = A[(size_t)k * 128 + col];
        else if (k < 256) f = B[(size_t)(k - 128) * 128 + col];
        else f = C1[(size_t)(k - 256) * 128 + col] + C2[(size_t)(k - 256) * 128 + col];
        o[j] = f2bits(f);
    }
    *(short8*)(dst + ((size_t)blockIdx.x * 64 + l) * 8) = o;
}

__global__ void k_foldW(float* __restrict__ dst, const float* __restrict__ Wa,
                        const float* __restrict__ Wb, const float* __restrict__ Wo,
                        int colOff, int NC) {
    int k = blockIdx.x;
    int c = threadIdx.x;
    float a = 0.f;
    for (int t = 0; t < 128; ++t) {
        float w = Wa[(size_t)k * 128 + t];
        if (Wb) w += Wb[(size_t)k * 128 + t];
        a += w * Wo[t * 16 + c];
    }
    dst[(size_t)k * NC + colOff + c] = a;
}

__global__ void k_bfold(float* __restrict__ dst, const float* __restrict__ bl1,
                        const float* __restrict__ bl2, const float* __restrict__ Wo,
                        const float* __restrict__ bo) {
    int c = threadIdx.x;
    float a = 0.f;
    for (int t = 0; t < 128; ++t) a += (bl1[t] + bl2[t]) * Wo[t * 16 + c];
    dst[c] = a + bo[c];
}

__global__ void k_addbias(float* __restrict__ dst, const float* __restrict__ a,
                          const float* __restrict__ b) {
    int i = threadIdx.x;
    dst[i] = a[i] + b[i];
}

// ---- u8 gather-mean, 16-lanes-per-node: lane owns 8 contiguous cols (uint2) ----
// One wave instruction covers 4 full rows (coalesced) -> 8 lines/instr, and
// loop length = this lane's node degree (max over 4 nodes/wave, not 16).
__device__ __forceinline__ void gmean8(const uchar* __restrict__ X8,
                                       const float* __restrict__ scale,
                                       const int* __restrict__ off,
                                       const int* __restrict__ esrc,
                                       int node, int ch, float m[8]) {
#pragma unroll
    for (int i = 0; i < 8; ++i) m[i] = 0.f;
    float S = 0.f;
    const int s = off[node], e = off[node + 1];
    int j = s;
    for (; j + 4 <= e; j += 4) {
        const int i0 = esrc[j], i1 = esrc[j + 1], i2 = esrc[j + 2], i3 = esrc[j + 3];
        const float s0 = scale[i0], s1 = scale[i1], s2 = scale[i2], s3 = scale[i3];
        uint2 v0 = *(const uint2*)(X8 + (size_t)i0 * HD + ch * 8);
        uint2 v1 = *(const uint2*)(X8 + (size_t)i1 * HD + ch * 8);
        uint2 v2 = *(const uint2*)(X8 + (size_t)i2 * HD + ch * 8);
        uint2 v3 = *(const uint2*)(X8 + (size_t)i3 * HD + ch * 8);
        S += (s0 + s1) + (s2 + s3);
#pragma unroll
        for (int i = 0; i < 4; ++i) {
            m[i]     += s0 * (float)((v0.x >> (8 * i)) & 0xffu)
                      + s1 * (float)((v1.x >> (8 * i)) & 0xffu)
                      + s2 * (float)((v2.x >> (8 * i)) & 0xffu)
                      + s3 * (float)((v3.x >> (8 * i)) & 0xffu);
            m[4 + i] += s0 * (float)((v0.y >> (8 * i)) & 0xffu)
                      + s1 * (float)((v1.y >> (8 * i)) & 0xffu)
                      + s2 * (float)((v2.y >> (8 * i)) & 0xffu)
                      + s3 * (float)((v3.y >> (8 * i)) & 0xffu);
        }
    }
    for (; j < e; ++j) {
        const int i0 = esrc[j];
        const float s0 = scale[i0];
        uint2 v = *(const uint2*)(X8 + (size_t)i0 * HD + ch * 8);
        S += s0;
#pragma unroll
        for (int i = 0; i < 4; ++i) {
            m[i]     = fmaf(s0, (float)((v.x >> (8 * i)) & 0xffu), m[i]);
            m[4 + i] = fmaf(s0, (float)((v.y >> (8 * i)) & 0xffu), m[4 + i]);
        }
    }
    const int d = e - s;
    const float inv = 1.f / (float)(d > 0 ? d : 1);
    const float corr = 128.f * S;
#pragma unroll
    for (int i = 0; i < 8; ++i) m[i] = (m[i] - corr) * inv;
}

// ================= merged SAGE layer-0 + folded layer-1 projection =================
// block = 16 nodes. Phase 1: each wave gathers 4 nodes (16 lanes/node) -> LDS
// tiles. Phase 2: waves split the layer-0 MFMA nt-tiles (self term bf16).
// Phase 3: bias+leaky -> tileO. Phase 4: fold-MFMA -> Y.
__global__ __launch_bounds__(256) void k_sage_all(
        const short* __restrict__ hu, const short* __restrict__ hi,
        const uchar* __restrict__ hu8, const float* __restrict__ scU,
        const uchar* __restrict__ hi8, const float* __restrict__ scI,
        const int* __restrict__ off_rates, const int* __restrict__ esrc_rates,
        const int* __restrict__ off_rated, const int* __restrict__ esrc_rated,
        const int* __restrict__ off_fol, const int* __restrict__ esrc_fol,
        const short* __restrict__ WpI, const float* __restrict__ biasI,
        const short* __restrict__ pYI,
        const short* __restrict__ WpU, const float* __restrict__ biasU,
        const short* __restrict__ pYU,
        short* __restrict__ YI, short* __restrict__ YZ, int gU) {
    __shared__ short tileA[16 * LROW];
    __shared__ short tileB[16 * LROW];
    __shared__ short tileO[16 * LROW];
    const int lane = threadIdx.x & 63;
    const int wv = threadIdx.x >> 6;
    const int nl = lane >> 4;        // node-local within wave (0..3)
    const int ch = lane & 15;        // col-chunk (8 cols each)
    const int colL = lane & 15;
    const int g = lane >> 4;

    if ((int)blockIdx.x < gU) {
        // ---------------- user path ----------------
        const int r0 = blockIdx.x * 16;
        const int lnode = wv * 4 + nl;          // 0..15
        int node = r0 + lnode;
        if (node >= NU) node = NU - 1;

        float m[8];
        gmean8(hi8, scI, off_rated, esrc_rated, node, ch, m);
#pragma unroll
        for (int i = 0; i < 8; ++i) tileA[lnode * LROW + ch * 8 + i] = f2bits(m[i]);
        gmean8(hu8, scU, off_fol, esrc_fol, node, ch, m);
#pragma unroll
        for (int i = 0; i < 8; ++i) tileB[lnode * LROW + ch * 8 + i] = f2bits(m[i]);
        __syncthreads();

        // phase 2: A-frags (rows = block nodes 0..15) + self term; waves split nt
        short8 afrag[12];
        {
            const short* ra = tileA + colL * LROW + g * 8;
            const short* rb = tileB + colL * LROW + g * 8;
#pragma unroll
            for (int kb = 0; kb < 4; ++kb) {
                afrag[kb] = *(const short8*)(ra + kb * 32);
                afrag[4 + kb] = *(const short8*)(rb + kb * 32);
            }
            int ar = r0 + colL;
            if (ar >= NU) ar = NU - 1;
            const short* p = hu + (size_t)ar * HD + g * 8;
#pragma unroll
            for (int kb = 0; kb < 4; ++kb) afrag[8 + kb] = *(const short8*)(p + kb * 32);
        }

        floatx4 acc[2];
#pragma unroll
        for (int t2 = 0; t2 < 2; ++t2) acc[t2] = (floatx4){0.f, 0.f, 0.f, 0.f};
        const short8* wp = (const short8*)WpU + lane;
#pragma unroll
        for (int t2 = 0; t2 < 2; ++t2) {
            const int nt = wv * 2 + t2;
#pragma unroll
            for (int kb = 0; kb < 12; ++kb) {
                short8 b = wp[(nt * 12 + kb) * 64];
                acc[t2] = __builtin_amdgcn_mfma_f32_16x16x32_bf16(afrag[kb], b, acc[t2], 0, 0, 0);
            }
        }
        // phase 3: bias + leaky -> tileO
#pragma unroll
        for (int t2 = 0; t2 < 2; ++t2) {
            const int nt = wv * 2 + t2;
            float bv = biasU[nt * 16 + colL];
#pragma unroll
            for (int r = 0; r < 4; ++r) {
                float x = acc[t2][r] + bv;
                x = (x >= 0.f) ? x : 0.01f * x;
                tileO[(g * 4 + r) * LROW + nt * 16 + colL] = f2bits(x);
            }
        }
        __syncthreads();

        // phase 4: fold (NT2 = 2, waves 0..1)
        if (wv < 2) {
            short8 af[4];
            const short* rp = tileO + colL * LROW + g * 8;
#pragma unroll
            for (int kb = 0; kb < 4; ++kb) af[kb] = *(const short8*)(rp + kb * 32);
            floatx4 a2 = (floatx4){0.f, 0.f, 0.f, 0.f};
            const short8* fp = (const short8*)pYU + lane;
#pragma unroll
            for (int kb = 0; kb < 4; ++kb) {
                short8 b = fp[(wv * 4 + kb) * 64];
                a2 = __builtin_amdgcn_mfma_f32_16x16x32_bf16(af[kb], b, a2, 0, 0, 0);
            }
            const int rbase = r0 + g * 4;
#pragma unroll
            for (int r = 0; r < 4; ++r) {
                int row = rbase + r;
                if (row < NU) YZ[(size_t)row * 32 + wv * 16 + colL] = f2bits(a2[r]);
            }
        }
    } else {
        // ---------------- item path ----------------
        const int b = blockIdx.x - gU;
        const int r0 = b * 16;
        const int lnode = wv * 4 + nl;
        int node = r0 + lnode;
        if (node >= NI) node = NI - 1;

        float m[8];
        gmean8(hu8, scU, off_rates, esrc_rates, node, ch, m);
#pragma unroll
        for (int i = 0; i < 8; ++i) tileA[lnode * LROW + ch * 8 + i] = f2bits(m[i]);
        __syncthreads();

        short8 afrag[8];
        {
            const short* ra = tileA + colL * LROW + g * 8;
#pragma unroll
            for (int kb = 0; kb < 4; ++kb) afrag[kb] = *(const short8*)(ra + kb * 32);
            int ar = r0 + colL;
            if (ar >= NI) ar = NI - 1;
            const short* p = hi + (size_t)ar * HD + g * 8;
#pragma unroll
            for (int kb = 0; kb < 4; ++kb) afrag[4 + kb] = *(const short8*)(p + kb * 32);
        }

        floatx4 acc[2];
#pragma unroll
        for (int t2 = 0; t2 < 2; ++t2) acc[t2] = (floatx4){0.f, 0.f, 0.f, 0.f};
        const short8* wp = (const short8*)WpI + lane;
#pragma unroll
        for (int t2 = 0; t2 < 2; ++t2) {
            const int nt = wv * 2 + t2;
#pragma unroll
            for (int kb = 0; kb < 8; ++kb) {
                short8 b = wp[(nt * 8 + kb) * 64];
                acc[t2] = __builtin_amdgcn_mfma_f32_16x16x32_bf16(afrag[kb], b, acc[t2], 0, 0, 0);
            }
        }
#pragma unroll
        for (int t2 = 0; t2 < 2; ++t2) {
            const int nt = wv * 2 + t2;
            float bv = biasI[nt * 16 + colL];
#pragma unroll
            for (int r = 0; r < 4; ++r) {
                float x = acc[t2][r] + bv;
                x = (x >= 0.f) ? x : 0.01f * x;
                tileO[(g * 4 + r) * LROW + nt * 16 + colL] = f2bits(x);
            }
        }
        __syncthreads();

        if (wv == 0) {
            short8 af[4];
            const short* rp = tileO + colL * LROW + g * 8;
#pragma unroll
            for (int kb = 0; kb < 4; ++kb) af[kb] = *(const short8*)(rp + kb * 32);
            floatx4 a2 = (floatx4){0.f, 0.f, 0.f, 0.f};
            const short8* fp = (const short8*)pYI + lane;
#pragma unroll
            for (int kb = 0; kb < 4; ++kb) {
                short8 b = fp[kb * 64];
                a2 = __builtin_amdgcn_mfma_f32_16x16x32_bf16(af[kb], b, a2, 0, 0, 0);
            }
            const int rbase = r0 + g * 4;
#pragma unroll
            for (int r = 0; r < 4; ++r) {
                int row = rbase + r;
                if (row < NI) YI[(size_t)row * 16 + colL] = f2bits(a2[r]);
            }
        }
    }
}

// ================= input projections (merged) + plain-u8 quantization =================
template <int KB1>
__device__ __forceinline__ void mm_body(int bid, const float* __restrict__ A1,
                                        const short* __restrict__ Wp,
                                        const float* __restrict__ bias,
                                        short* __restrict__ C,
                                        uchar* __restrict__ U8,
                                        float* __restrict__ scale, int M,
                                        int lane, int wv) {
    const int r0 = bid * 128 + wv * 32;
    const int g = lane >> 4;
    const int ksub = g * 8;
    const int colL = lane & 15;
    short8 afrag[2][KB1];
#pragma unroll
    for (int h = 0; h < 2; ++h) {
        int ar = r0 + h * 16 + colL;
        if (ar >= M) ar = M - 1;
        const float* p = A1 + (size_t)ar * (KB1 * 32) + ksub;
#pragma unroll
        for (int kb = 0; kb < KB1; ++kb) {
            short8 f;
#pragma unroll
            for (int j = 0; j < 8; ++j) f[j] = f2bits(p[kb * 32 + j]);
            afrag[h][kb] = f;
        }
    }
    floatx4 acc[2][8];
#pragma unroll
    for (int h = 0; h < 2; ++h)
#pragma unroll
        for (int nt = 0; nt < 8; ++nt) acc[h][nt] = (floatx4){0.f, 0.f, 0.f, 0.f};
    const short8* wp = (const short8*)Wp + lane;
#pragma unroll
    for (int nt = 0; nt < 8; ++nt)
#pragma unroll
        for (int kb = 0; kb < KB1; ++kb) {
            short8 b = wp[(nt * KB1 + kb) * 64];
            acc[0][nt] = __builtin_amdgcn_mfma_f32_16x16x32_bf16(afrag[0][kb], b, acc[0][nt], 0, 0, 0);
            acc[1][nt] = __builtin_amdgcn_mfma_f32_16x16x32_bf16(afrag[1][kb], b, acc[1][nt], 0, 0, 0);
        }
#pragma unroll
    for (int h = 0; h < 2; ++h) {
#pragma unroll
        for (int r = 0; r < 4; ++r) {
            const int row = r0 + h * 16 + g * 4 + r;
            float v[8];
            float m = 0.f;
#pragma unroll
            for (int nt = 0; nt < 8; ++nt) {
                v[nt] = acc[h][nt][r] + bias[nt * 16 + colL];
                m = fmaxf(m, fabsf(v[nt]));
            }
#pragma unroll
            for (int x = 1; x < 16; x <<= 1) m = fmaxf(m, __shfl_xor(m, x, 16));
            const float invq = (m > 0.f) ? 127.f / m : 0.f;
            if (row < M) {
#pragma unroll
                for (int nt = 0; nt < 8; ++nt) {
                    C[(size_t)row * HD + nt * 16 + colL] = f2bits(v[nt]);
                    U8[(size_t)row * HD + nt * 16 + colL] =
                        (uchar)((int)rintf(v[nt] * invq) + 128);
                }
                if (colL == 0) scale[row] = m * (1.f / 127.f);
            }
        }
    }
}

__global__ __launch_bounds__(256) void k_mm2(const float* __restrict__ xu,
                                             const short* __restrict__ pWu,
                                             const float* __restrict__ bu,
                                             short* __restrict__ hu,
                                             uchar* __restrict__ hu8,
                                             float* __restrict__ scU,
                                             const float* __restrict__ xi,
                                             const short* __restrict__ pWi,
                                             const float* __restrict__ bi,
                                             short* __restrict__ hi,
                                             uchar* __restrict__ hi8,
                                             float* __restrict__ scI, int gU2) {
    const int lane = threadIdx.x & 63;
    const int wv = threadIdx.x >> 6;
    if ((int)blockIdx.x < gU2)
        mm_body<2>(blockIdx.x, xu, pWu, bu, hu, hu8, scU, NU, lane, wv);
    else
        mm_body<4>(blockIdx.x - gU2, xi, pWi, bi, hi, hi8, scI, NI, lane, wv);
}

// ================= final output =================
__global__ __launch_bounds__(256) void k_out(const short* __restrict__ YZ,
                                             const short* __restrict__ YI,
                                             const int* __restrict__ off_f,
                                             const int* __restrict__ esrc_f,
                                             const int* __restrict__ off_r,
                                             const int* __restrict__ esrc_r,
                                             const float* __restrict__ bias16,
                                             float* __restrict__ out, int N) {
    int t = threadIdx.x;
    int node = blockIdx.x * 128 + (t >> 1);
    int half = t & 1;
    if (node >= N) return;
    const int c0 = half * 8;

    float a[8] = {0.f, 0.f, 0.f, 0.f, 0.f, 0.f, 0.f, 0.f};
    {
        const int s = off_f[node], e = off_f[node + 1];
        int j = s;
        for (; j + 4 <= e; j += 4) {
            short8 v0 = *(const short8*)(YZ + (size_t)esrc_f[j] * 32 + c0);
            short8 v1 = *(const short8*)(YZ + (size_t)esrc_f[j + 1] * 32 + c0);
            short8 v2 = *(const short8*)(YZ + (size_t)esrc_f[j + 2] * 32 + c0);
            short8 v3 = *(const short8*)(YZ + (size_t)esrc_f[j + 3] * 32 + c0);
#pragma unroll
            for (int i = 0; i < 8; ++i)
                a[i] += (bits2f(v0[i]) + bits2f(v1[i])) + (bits2f(v2[i]) + bits2f(v3[i]));
        }
        for (; j < e; ++j) {
            short8 v = *(const short8*)(YZ + (size_t)esrc_f[j] * 32 + c0);
#pragma unroll
            for (int i = 0; i < 8; ++i) a[i] += bits2f(v[i]);
        }
        int d = e - s;
        float inv = 1.f / (float)(d > 0 ? d : 1);
#pragma unroll
        for (int i = 0; i < 8; ++i) a[i] *= inv;
    }
    {
        float b[8] = {0.f, 0.f, 0.f, 0.f, 0.f, 0.f, 0.f, 0.f};
        const int s = off_r[node], e = off_r[node + 1];
        int j = s;
        for (; j + 4 <= e; j += 4) {
            short8 v0 = *(const short8*)(YI + (size_t)esrc_r[j] * 16 + c0);
            short8 v1 = *(const short8*)(YI + (size_t)esrc_r[j + 1] * 16 + c0);
            short8 v2 = *(const short8*)(YI + (size_t)esrc_r[j + 2] * 16 + c0);
            short8 v3 = *(const short8*)(YI + (size_t)esrc_r[j + 3] * 16 + c0);
#pragma unroll
            for (int i = 0; i < 8; ++i)
                b[i] += (bits2f(v0[i]) + bits2f(v1[i])) + (bits2f(v2[i]) + bits2f(v3[i]));
        }
        for (; j < e; ++j) {
            short8 v = *(const short8*)(YI + (size_t)esrc_r[j] * 16 + c0);
#pragma unroll
            for (int i = 0; i < 8; ++i) b[i] += bits2f(v[i]);
        }
        int d = e - s;
        float inv = 1.f / (float)(d > 0 ? d : 1);
#pragma unroll
        for (int i = 0; i < 8; ++i) a[i] += b[i] * inv;
    }
    short8 z = *(const short8*)(YZ + (size_t)node * 32 + 16 + c0);
#pragma unroll
    for (int i = 0; i < 8; ++i)
        out[(size_t)node * 16 + c0 + i] = a[i] + bits2f(z[i]) + bias16[c0 + i];
}

// ================= launch =================
extern "C" void kernel_launch(void* const* d_in, const int* in_sizes, int n_in,
                              void* d_out, int out_size, void* d_ws, size_t ws_size,
                              hipStream_t stream) {
    const float* x_user    = (const float*)d_in[0];
    const float* x_item    = (const float*)d_in[1];
    const int* src_rates   = (const int*)d_in[2];
    const int* dst_rates   = (const int*)d_in[3];
    const int* src_rated   = (const int*)d_in[4];
    const int* dst_rated   = (const int*)d_in[5];
    const int* src_fol     = (const int*)d_in[6];
    const int* dst_fol     = (const int*)d_in[7];
    const float* W_in_user = (const float*)d_in[8];
    const float* b_in_user = (const float*)d_in[9];
    const float* W_in_item = (const float*)d_in[10];
    const float* b_in_item = (const float*)d_in[11];
    const float* Wl_rates  = (const float*)d_in[12];
    const float* bl_rates  = (const float*)d_in[13];
    const float* Wr_rates  = (const float*)d_in[14];
    const float* Wl_rated  = (const float*)d_in[15];
    const float* bl_rated  = (const float*)d_in[16];
    const float* Wr_rated  = (const float*)d_in[17];
    const float* Wl_fol    = (const float*)d_in[18];
    const float* bl_fol    = (const float*)d_in[19];
    const float* Wr_fol    = (const float*)d_in[20];
    const float* W_out     = (const float*)d_in[21];
    const float* b_out     = (const float*)d_in[22];
    float* out = (float*)d_out;

    char* w = (char*)d_ws;
    size_t used = 0;
    auto alloc = [&](size_t bytes) -> void* {
        void* p = w + used;
        used += (bytes + 255) & ~(size_t)255;
        return p;
    };
    short* hu_a = (short*)alloc((size_t)NU * HD * 2);
    short* hi_a = (short*)alloc((size_t)NI * HD * 2);
    uchar* hu8  = (uchar*)alloc((size_t)NU * HD);
    uchar* hi8  = (uchar*)alloc((size_t)NI * HD);
    float* scU  = (float*)alloc((size_t)NU * 4);
    float* scI  = (float*)alloc((size_t)NI * 4);
    short* YZ   = (short*)alloc((size_t)NU * 32 * 2);
    short* YI   = (short*)alloc((size_t)NI * 16 * 2);

    int* off_rates  = (int*)alloc((size_t)(NI + 1) * 4);
    int* esrc_rates = (int*)alloc((size_t)NEDGE * 4);
    int* off_rated  = (int*)alloc((size_t)(NU + 1) * 4);
    int* esrc_rated = (int*)alloc((size_t)NEDGE * 4);
    int* off_fol    = (int*)alloc((size_t)(NU + 1) * 4);
    int* esrc_fol   = (int*)alloc((size_t)NEDGE * 4);
    int* pairs      = (int*)alloc((size_t)3 * NEDGE * 4);
    int* cnts       = (int*)alloc((size_t)3 * NBLK * MAXBUK * 4);
    int* base       = (int*)alloc((size_t)3 * NBLK * MAXBUK * 4);
    int* bbase      = (int*)alloc((size_t)3 * 257 * 4);

    short* pWu     = (short*)alloc(8 * 2 * 64 * 8 * 2);
    short* pWi     = (short*)alloc(8 * 4 * 64 * 8 * 2);
    short* pRates0 = (short*)alloc(8 * 8 * 64 * 8 * 2);
    short* pUser0  = (short*)alloc(8 * 12 * 64 * 8 * 2);
    float* WfU     = (float*)alloc(128 * 32 * 4);
    float* WfI     = (float*)alloc(128 * 16 * 4);
    short* pYU     = (short*)alloc(2 * 4 * 64 * 8 * 2);
    short* pYI     = (short*)alloc(1 * 4 * 64 * 8 * 2);
    float* bSum0   = (float*)alloc(128 * 4);
    float* bias16  = (float*)alloc(16 * 4);
    if (used > ws_size) return;   // diagnostic signature: output stays zero

    // ---- CSR build v3 (contention-free, all 3 graphs merged) ----
    k_cnt3<<<3 * NBLK, 256, 0, stream>>>(dst_rates, dst_rated, dst_fol, cnts);
    k_bases3<<<3, 256, 0, stream>>>(cnts, base, bbase, off_rates, off_rated, off_fol);
    k_part3<<<3 * NBLK, 256, 0, stream>>>(src_rates, dst_rates, src_rated, dst_rated,
                                          src_fol, dst_fol, base, pairs);
    k_place3<<<NB_I + 2 * NB_U, 256, 0, stream>>>(pairs, bbase,
                                                  off_rates, esrc_rates,
                                                  off_rated, esrc_rated,
                                                  off_fol, esrc_fol);

    // ---- weight prep (separate proven kernels) ----
    k_pack<<<16, 64, 0, stream>>>(pWu, W_in_user, nullptr, nullptr, 64, 0, 128);
    k_pack<<<32, 64, 0, stream>>>(pWi, W_in_item, nullptr, nullptr, 128, 0, 128);
    k_pack<<<64, 64, 0, stream>>>(pRates0, Wl_rates, Wr_rates, nullptr, 128, 128, 128);
    k_pack3<<<96, 64, 0, stream>>>(pUser0, Wl_rated, Wl_fol, Wr_rated, Wr_fol);
    k_addbias<<<1, 128, 0, stream>>>(bSum0, bl_rated, bl_fol);
    k_foldW<<<128, 16, 0, stream>>>(WfU, Wl_fol + HH,   nullptr,     W_out, 0, 32);
    k_foldW<<<128, 16, 0, stream>>>(WfU, Wr_rated + HH, Wr_fol + HH, W_out, 16, 32);
    k_foldW<<<128, 16, 0, stream>>>(WfI, Wl_rated + HH, nullptr,     W_out, 0, 16);
    k_pack<<<8, 64, 0, stream>>>(pYU, WfU, nullptr, nullptr, 128, 0, 32);
    k_pack<<<4, 64, 0, stream>>>(pYI, WfI, nullptr, nullptr, 128, 0, 16);
    k_bfold<<<1, 16, 0, stream>>>(bias16, bl_rated + 128, bl_fol + 128, W_out, b_out);

    const int gU2 = (NU + 127) / 128;  // 1563
    const int gI2 = (NI + 127) / 128;  // 782
    const int gU  = (NU + 15) / 16;    // 12500
    const int gI  = (NI + 15) / 16;    // 6250

    // ---- input projections (merged) + u8 quantization ----
    k_mm2<<<gU2 + gI2, 256, 0, stream>>>(x_user, pWu, b_in_user, hu_a, hu8, scU,
                                         x_item, pWi, b_in_item, hi_a, hi8, scI, gU2);

    // ---- merged layer-0 SAGE (coalesced u8 gathers) + folded layer-1 projection ----
    k_sage_all<<<gU + gI, 256, 0, stream>>>(
        hu_a, hi_a, hu8, scU, hi8, scI,
        off_rates, esrc_rates, off_rated, esrc_rated, off_fol, esrc_fol,
        pRates0, bl_rates, pYI, pUser0, bSum0, pYU, YI, YZ, gU);

    // ---- final: dual 16-dim gather-mean + residual + bias -> fp32 out ----
    k_out<<<(NU + 127) / 128, 256, 0, stream>>>(
        YZ, YI, off_fol, esrc_fol, off_rated, esrc_rated, bias16, out, NU);
}